// Round 1
// baseline (59.391 us; speedup 1.0000x reference)
//
#include <hip/hip_runtime.h>

// SamplerQNN collapses analytically:
//   out[b][w] = prod_{i=0..w} cos(x[b][i] + theta[i])   for w >= 1
//   out[b][0] = prod_{i=1..9} cos(x[b][i] + theta[i])
// Derivation: CNOTs are basis permutations over GF(2); <Z_w> factorizes into
// a product of cos(2a_i) = cos(x_i + theta_i) over the XOR-support of bit w
// under the inverse CNOT-chain transform. Chain 0->1..8->9, 9->0 gives
// S_w = {0..w} (w>=1), S_0 = {1..9}.

constexpr int NQ = 10;
constexpr int ROWS = 256;          // rows (batch elements) per block
constexpr int STRIDE = NQ + 1;     // LDS row stride: 11 breaks stride-10 4-way bank conflict

__global__ __launch_bounds__(ROWS) void qnn_kernel(const float* __restrict__ x,
                                                   const float* __restrict__ theta,
                                                   float* __restrict__ out,
                                                   int B) {
    __shared__ float sx[ROWS * STRIDE];
    __shared__ float th[NQ];
    const int tid = threadIdx.x;
    const long long gbase = (long long)blockIdx.x * (ROWS * NQ);
    const long long total = (long long)B * NQ;

    if (tid < NQ) th[tid] = theta[tid];

    // Coalesced global -> LDS (de-interleave 10-float rows into padded rows)
    #pragma unroll
    for (int i = 0; i < NQ; ++i) {
        long long k = (long long)i * ROWS + tid;   // 0..2559 within block
        if (gbase + k < total) {
            float v = x[gbase + k];
            int r = (int)(k / NQ);
            int c = (int)(k - (long long)r * NQ);
            sx[r * STRIDE + c] = v;
        }
    }
    __syncthreads();

    const int row = blockIdx.x * ROWS + tid;
    float res[NQ];
    if (row < B) {
        float t[NQ];
        #pragma unroll
        for (int j = 0; j < NQ; ++j)
            t[j] = __cosf(sx[tid * STRIDE + j] + th[j]);
        // prefix products: out[w] = t0*...*tw  (w>=1)
        float p = t[0];
        #pragma unroll
        for (int w = 1; w < NQ; ++w) { p *= t[w]; res[w] = p; }
        // out[0] = t1*...*t9
        float s = t[1];
        #pragma unroll
        for (int i = 2; i < NQ; ++i) s *= t[i];
        res[0] = s;
    }
    __syncthreads();   // reuse sx for output staging

    if (row < B) {
        #pragma unroll
        for (int j = 0; j < NQ; ++j) sx[tid * STRIDE + j] = res[j];
    }
    __syncthreads();

    // LDS -> coalesced global stores
    #pragma unroll
    for (int i = 0; i < NQ; ++i) {
        long long k = (long long)i * ROWS + tid;
        if (gbase + k < total) {
            int r = (int)(k / NQ);
            int c = (int)(k - (long long)r * NQ);
            out[gbase + k] = sx[r * STRIDE + c];
        }
    }
}

extern "C" void kernel_launch(void* const* d_in, const int* in_sizes, int n_in,
                              void* d_out, int out_size, void* d_ws, size_t ws_size,
                              hipStream_t stream) {
    const float* x = (const float*)d_in[0];
    const float* theta = (const float*)d_in[1];
    float* out = (float*)d_out;
    const int B = in_sizes[0] / NQ;                 // 65536
    const int grid = (B + ROWS - 1) / ROWS;         // 256 blocks
    qnn_kernel<<<grid, ROWS, 0, stream>>>(x, theta, out, B);
}

// Round 2
// 56.672 us; speedup vs baseline: 1.0480x; 1.0480x over previous
//
#include <hip/hip_runtime.h>

// SamplerQNN collapses analytically:
//   out[b][w] = prod_{i=0..w} cos(x[b][i] + theta[i])   for w >= 1
//   out[b][0] = prod_{i=1..9} cos(x[b][i] + theta[i])
// Derivation: CNOTs are basis permutations over GF(2); <Z_w> factorizes into
// a product of cos(2a_i) = cos(x_i + theta_i) over the XOR-support of bit w
// under the inverse CNOT-chain transform. Chain 0->1..8->9, 9->0 gives
// S_w = {0..w} (w>=1), S_0 = {1..9}.
//
// R1: direct float2x5 global loads/stores per row (rows are 40 B, 8 B aligned)
// replace the LDS de-interleave + 3 barriers + 20 int-divides of R0. theta
// reads use constant indices on a uniform pointer -> scalar s_load path.

constexpr int NQ = 10;
constexpr int BLOCK = 256;

__global__ __launch_bounds__(BLOCK) void qnn_kernel(const float* __restrict__ x,
                                                    const float* __restrict__ theta,
                                                    float* __restrict__ out,
                                                    int B) {
    const int row = blockIdx.x * BLOCK + threadIdx.x;
    if (row >= B) return;

    const float2* __restrict__ xr = (const float2*)(x + (size_t)row * NQ);
    float2 v0 = xr[0];
    float2 v1 = xr[1];
    float2 v2 = xr[2];
    float2 v3 = xr[3];
    float2 v4 = xr[4];

    float t0 = __cosf(v0.x + theta[0]);
    float t1 = __cosf(v0.y + theta[1]);
    float t2 = __cosf(v1.x + theta[2]);
    float t3 = __cosf(v1.y + theta[3]);
    float t4 = __cosf(v2.x + theta[4]);
    float t5 = __cosf(v2.y + theta[5]);
    float t6 = __cosf(v3.x + theta[6]);
    float t7 = __cosf(v3.y + theta[7]);
    float t8 = __cosf(v4.x + theta[8]);
    float t9 = __cosf(v4.y + theta[9]);

    // prefix products p_w = t0*...*tw
    float p1 = t0 * t1;
    float p2 = p1 * t2;
    float p3 = p2 * t3;
    float p4 = p3 * t4;
    float p5 = p4 * t5;
    float p6 = p5 * t6;
    float p7 = p6 * t7;
    float p8 = p7 * t8;
    float p9 = p8 * t9;
    // out[0] = t1*...*t9 (suffix without t0)
    float s = t1 * t2;
    s *= t3; s *= t4; s *= t5; s *= t6; s *= t7; s *= t8; s *= t9;

    float2* __restrict__ orow = (float2*)(out + (size_t)row * NQ);
    orow[0] = make_float2(s,  p1);
    orow[1] = make_float2(p2, p3);
    orow[2] = make_float2(p4, p5);
    orow[3] = make_float2(p6, p7);
    orow[4] = make_float2(p8, p9);
}

extern "C" void kernel_launch(void* const* d_in, const int* in_sizes, int n_in,
                              void* d_out, int out_size, void* d_ws, size_t ws_size,
                              hipStream_t stream) {
    const float* x = (const float*)d_in[0];
    const float* theta = (const float*)d_in[1];
    float* out = (float*)d_out;
    const int B = in_sizes[0] / NQ;                 // 65536
    const int grid = (B + BLOCK - 1) / BLOCK;       // 256 blocks
    qnn_kernel<<<grid, BLOCK, 0, stream>>>(x, theta, out, B);
}